// Round 13
// baseline (1391.921 us; speedup 1.0000x reference)
//
#include <hip/hip_runtime.h>
#include <hip/hip_bf16.h>
#include <stdint.h>

// ---------------- constants ----------------
#define DIMC 512
#define HEADS 16
#define HEAD_DIM 32
#define NTOK 49            // tokens per window (7x7)
#define SCALE 0.17677669529663687f   // 1/sqrt(32)
#define LOG2E 1.4426950408889634f
#define MTOK 200704        // 4096 * 49

typedef unsigned short u16;
typedef short bf16x8 __attribute__((ext_vector_type(8)));
typedef float f32x4 __attribute__((ext_vector_type(4)));
typedef u16 u16x4 __attribute__((ext_vector_type(4)));
typedef u16 u16x8 __attribute__((ext_vector_type(8)));

#define MFMA16(a, b, c) __builtin_amdgcn_mfma_f32_16x16x32_bf16((a), (b), (c), 0, 0, 0)

__device__ __forceinline__ u16 f2bf(float f) {
  __hip_bfloat16 h = __float2bfloat16(f);   // RNE
  u16 u;
  __builtin_memcpy(&u, &h, 2);
  return u;
}

__device__ __forceinline__ float bf2f(u16 u) {
  const uint32_t b = ((uint32_t)u) << 16;
  float f;
  __builtin_memcpy(&f, &b, 4);
  return f;
}

// async global->LDS, 16 bytes per lane (wave-uniform LDS base + lane*16)
__device__ __forceinline__ void gld16(const void* g, void* l) {
  __builtin_amdgcn_global_load_lds(
      (const __attribute__((address_space(1))) uint32_t*)g,
      (__attribute__((address_space(3))) uint32_t*)l, 16, 0, 0);
}

// ---------------- fp32 -> bf16 convert (grid-stride, 8 elems/thread/iter) ----
__global__ void cvt_f32_bf16(const float* __restrict__ in, u16* __restrict__ out, int n) {
  const int stride = gridDim.x * blockDim.x;
  for (int i = blockIdx.x * blockDim.x + threadIdx.x; i * 8 < n; i += stride) {
    const float4 v0 = ((const float4*)(in + i * 8))[0];
    const float4 v1 = ((const float4*)(in + i * 8))[1];
    u16x8 r;
    r[0] = f2bf(v0.x); r[1] = f2bf(v0.y); r[2] = f2bf(v0.z); r[3] = f2bf(v0.w);
    r[4] = f2bf(v1.x); r[5] = f2bf(v1.y); r[6] = f2bf(v1.z); r[7] = f2bf(v1.w);
    *(u16x8*)(out + i * 8) = r;
  }
}

// ---- bias+mask precompute, C-FRAGMENT order, bf16, PRE-SCALED by log2e ----
__global__ void biasmask_kernel(const float* __restrict__ table, const float* __restrict__ mask,
                                u16* __restrict__ bm) {
  const int wm = blockIdx.x >> 4;   // 0..63
  const int h  = blockIdx.x & 15;   // 0..15
  for (int e = threadIdx.x; e < 4096; e += 256) {
    const int r = e & 3, lane = (e >> 2) & 63, fj = (e >> 8) & 3, fi = e >> 10;
    const int row = fi * 16 + (lane >> 4) * 4 + r;
    const int col = fj * 16 + (lane & 15);
    float v;
    if (row < NTOK && col < NTOK) {
      const int yi = row / 7, xi = row % 7, yj = col / 7, xj = col % 7;
      const int idx = (yi - yj + 6) * 13 + (xi - xj + 6);
      v = (table[idx * HEADS + h] + mask[wm * (NTOK * NTOK) + row * NTOK + col]) * LOG2E;
    } else {
      v = -1e30f;   // pad -> exp2 == exact 0
    }
    bm[(size_t)blockIdx.x * 4096 + e] = f2bf(v);
  }
}

// ---------------- GEMM: C[M,N] = A[M,K] @ B[N,K]^T + bias (all bf16 in) ------
// R2-PROVEN structure, FROZEN. HEADMAJOR epilogue (gemm1): scatter to
// [head][token][96] (q|k|v per head) for dense attn reads.
template<bool OUT_BF16, bool HEADMAJOR>
__global__ void gemm_bf16(const u16* __restrict__ Ap, const u16* __restrict__ Bp,
                          const float* __restrict__ bias, void* __restrict__ Cp,
                          int M, int N, int K, int nxt) {
  __shared__ u16 As[128 * 64];
  __shared__ u16 Bs[128 * 64];
  const int t = threadIdx.x;
  const int lane = t & 63;
  const int q = gridDim.x >> 3;
  const int lin = blockIdx.x;
  const int l = (lin & 7) * q + (lin >> 3);
  const int bm0 = (l / nxt) * 128;
  const int bn0 = (l % nxt) * 128;
  const int wv = t >> 6, wr = wv >> 1, wc = wv & 1;
  const int lr = lane & 15, lg = lane >> 4;

  f32x4 acc[4][4] = {};

  int soff[4];
#pragma unroll
  for (int k = 0; k < 4; ++k) {
    const int c = t + 256 * k;
    const int row = c >> 3, sub = c & 7;
    soff[k] = ((sub ^ (row & 7)) * 8);
  }

  const int nK = K >> 6;
  for (int kt = 0; kt < nK; ++kt) {
    const int k0 = kt << 6;
    __syncthreads();
#pragma unroll
    for (int k = 0; k < 4; ++k) {
      const int c = t + 256 * k;
      const int row = c >> 3;
      gld16(Ap + (size_t)(bm0 + row) * K + k0 + soff[k], As + c * 8);
      gld16(Bp + (size_t)(bn0 + row) * K + k0 + soff[k], Bs + c * 8);
    }
    __syncthreads();

#pragma unroll
    for (int kk = 0; kk < 2; ++kk) {
      bf16x8 af[4], bfr[4];
#pragma unroll
      for (int i = 0; i < 4; ++i) {
        const int row = wr * 64 + i * 16 + lr;
        af[i] = *(const bf16x8*)&As[row * 64 + (((kk * 4 + lg) ^ (row & 7)) << 3)];
      }
#pragma unroll
      for (int j = 0; j < 4; ++j) {
        const int row = wc * 64 + j * 16 + lr;
        bfr[j] = *(const bf16x8*)&Bs[row * 64 + (((kk * 4 + lg) ^ (row & 7)) << 3)];
      }
#pragma unroll
      for (int i = 0; i < 4; ++i)
#pragma unroll
        for (int j = 0; j < 4; ++j)
          acc[i][j] = MFMA16(af[i], bfr[j], acc[i][j]);
    }
  }

  // epilogue: D row = (lane>>4)*4 + r, col = lane&15 (m89-verified layout)
#pragma unroll
  for (int j = 0; j < 4; ++j) {
    const int col = bn0 + wc * 64 + j * 16 + lr;
    const float bv = bias[col];
    const int p = col >> 9, hh = (col & 511) >> 5, d = col & 31;
    const float sc = (HEADMAJOR && p == 0) ? SCALE * LOG2E : 1.0f;
#pragma unroll
    for (int i = 0; i < 4; ++i) {
      const int row0 = bm0 + wr * 64 + i * 16 + lg * 4;
#pragma unroll
      for (int r = 0; r < 4; ++r) {
        const float val = (acc[i][j][r] + bv) * sc;
        if (HEADMAJOR) {
          ((u16*)Cp)[((size_t)hh * MTOK + row0 + r) * 96 + p * 32 + d] = f2bf(val);
        } else if (OUT_BF16) {
          ((u16*)Cp)[(size_t)(row0 + r) * N + col] = f2bf(val);
        } else {
          ((float*)Cp)[(size_t)(row0 + r) * N + col] = val;
        }
      }
    }
  }
}

// ---------------- fused window attention (v5: head-major input) ----------
// 1 wave per (window, head). qkv: [head][token][96] bf16. bid-mask lets the
// R13 diagnostic run a 2x grid (blocks i and i+16384 do identical work).
__launch_bounds__(256, 4)
__global__ void attn_win(const u16* __restrict__ qkv, const u16* __restrict__ bmfrag,
                         u16* __restrict__ aout) {
  __shared__ u16 P[4][64 * 64];    // per-wave P tile, chunk-XOR swizzled
  const int t = threadIdx.x, lane = t & 63, wv = t >> 6;
  const int lr = lane & 15, lg = lane >> 4;
  const int bid = blockIdx.x & 16383;
  const int w = bid >> 2;
  const int h = ((bid & 3) << 2) + wv;
  const size_t baseh = ((size_t)h * MTOK + (size_t)w * NTOK) * 96;

  // acc init = bias+mask fragments (bf16, fragment-ordered, 8B/lane)
  const u16* bmp = bmfrag + (((size_t)(w & 63) * 16 + h) << 12);
  f32x4 s[4][4];
#pragma unroll
  for (int i = 0; i < 4; ++i)
#pragma unroll
    for (int j = 0; j < 4; ++j) {
      const u16x4 b4 = *(const u16x4*)&bmp[((i * 4 + j) * 64 + lane) * 4];
#pragma unroll
      for (int r = 0; r < 4; ++r) s[i][j][r] = bf2f(b4[r]);
    }

  const bf16x8 zf = {};
  bf16x8 qf[4], kf[4];
#pragma unroll
  for (int i = 0; i < 4; ++i) {
    const int row = i * 16 + lr;
    const size_t roff = baseh + (size_t)row * 96 + lg * 8;
    qf[i] = (row < NTOK) ? *(const bf16x8*)&qkv[roff] : zf;        // Q(row, d..)
    kf[i] = (row < NTOK) ? *(const bf16x8*)&qkv[roff + 32] : zf;   // K(row, d..)
  }

  __builtin_amdgcn_s_setprio(1);
#pragma unroll
  for (int i = 0; i < 4; ++i)
#pragma unroll
    for (int j = 0; j < 4; ++j)
      s[i][j] = MFMA16(qf[i], kf[j], s[i][j]);   // S = q'K^T + (bias+mask)*log2e
  __builtin_amdgcn_s_setprio(0);

  // P = exp2(S) (unnormalized) -> LDS bf16, C/D-layout scatter, chunk-XOR
  u16* Pw = &P[wv][0];
#pragma unroll
  for (int i = 0; i < 4; ++i)
#pragma unroll
    for (int r = 0; r < 4; ++r) {
      const int ii = i * 16 + lg * 4 + r;
#pragma unroll
      for (int j = 0; j < 4; ++j) {
        const int jj = j * 16 + lr;
        Pw[ii * 64 + (((jj >> 3) ^ (ii & 7)) << 3) + (jj & 7)] =
            f2bf(__builtin_amdgcn_exp2f(s[i][j][r]));
      }
    }

  // V as B-fragments, direct from global (after s[] dies; TLP hides latency).
  bf16x8 vf[2][2];
#pragma unroll
  for (int ks = 0; ks < 2; ++ks)
#pragma unroll
    for (int dn = 0; dn < 2; ++dn)
#pragma unroll
      for (int e = 0; e < 8; ++e) {
        int kk = ks * 32 + lg * 8 + e;
        kk = kk < NTOK ? kk : 0;
        vf[ks][dn][e] = (short)qkv[baseh + (size_t)kk * 96 + 64 + dn * 16 + lr];
      }

  // PV + row-sum: out[i][d] = sum_k P[i][k] V[k][d]; osum[i] = sum_k P[i][k]
  bf16x8 ones;
#pragma unroll
  for (int e = 0; e < 8; ++e) ones[e] = (short)0x3F80;  // bf16 1.0
  f32x4 o[4][2] = {};
  f32x4 osum[4] = {};
#pragma unroll
  for (int ks = 0; ks < 2; ++ks) {
    __builtin_amdgcn_s_setprio(1);
#pragma unroll
    for (int i = 0; i < 4; ++i) {
      const int row = i * 16 + lr;
      const bf16x8 pa = *(const bf16x8*)&Pw[row * 64 + (((ks * 4 + lg) ^ (row & 7)) << 3)];
#pragma unroll
      for (int dn = 0; dn < 2; ++dn)
        o[i][dn] = MFMA16(pa, vf[ks][dn], o[i][dn]);
      osum[i] = MFMA16(pa, ones, osum[i]);     // row-sum in C-layout
    }
    __builtin_amdgcn_s_setprio(0);
  }

  // store attention output (normalize here) -> [token][h*32+d] bf16
#pragma unroll
  for (int i = 0; i < 4; ++i)
#pragma unroll
    for (int r = 0; r < 4; ++r) {
      const int row = i * 16 + lg * 4 + r;
      if (row < NTOK) {
        const float rinv = __builtin_amdgcn_rcpf(osum[i][r]);
        const size_t ob = ((size_t)w * NTOK + row) * DIMC + h * HEAD_DIM;
#pragma unroll
        for (int dn = 0; dn < 2; ++dn)
          aout[ob + dn * 16 + lr] = f2bf(o[i][dn][r] * rinv);
      }
    }
}

// ---------------- launch ----------------
extern "C" void kernel_launch(void* const* d_in, const int* in_sizes, int n_in,
                              void* d_out, int out_size, void* d_ws, size_t ws_size,
                              hipStream_t stream) {
  const float* x      = (const float*)d_in[0];   // (4096,49,512)
  const float* mask   = (const float*)d_in[1];   // (64,49,49)
  const float* qkv_w  = (const float*)d_in[2];   // (1536,512)
  const float* qkv_b  = (const float*)d_in[3];   // (1536,)
  const float* table  = (const float*)d_in[4];   // (169,16)
  const float* proj_w = (const float*)d_in[5];   // (512,512)
  const float* proj_b = (const float*)d_in[6];   // (512,)
  float* out = (float*)d_out;

  const int M = MTOK;   // 200704

  char* ws = (char*)d_ws;
  u16*   qkv_bf   = (u16*)ws;                         // 16*200704*96*2 = 616,562,688
  u16*   wqkv_bf  = (u16*)(ws + 616562688ull);        // 1536*512*2    = 1,572,864
  u16*   wproj_bf = (u16*)(ws + 618135552ull);        // 512*512*2     = 524,288
  u16*   biasmask = (u16*)(ws + 618659840ull);        // 1024*4096*2   = 8,388,608
  // x_bf and attn_bf SHARE this region (disjoint lifetimes, same size):
  u16*   x_bf     = (u16*)(ws + 627048448ull);        // 200704*512*2  = 205,520,896
  u16*   attn_bf  = x_bf;
  // total 832,569,344 bytes

  cvt_f32_bf16<<<768, 256, 0, stream>>>(qkv_w, wqkv_bf, 1536 * 512);
  cvt_f32_bf16<<<256, 256, 0, stream>>>(proj_w, wproj_bf, 512 * 512);
  biasmask_kernel<<<1024, 256, 0, stream>>>(table, mask, biasmask);
  cvt_f32_bf16<<<1792, 256, 0, stream>>>(x, x_bf, M * DIMC);

  // QKV GEMM -> head-major layout: (M,1536,512); grid 1568*12 = 18816 (%8==0)
  gemm_bf16<true, true><<<1568 * 12, 256, 0, stream>>>(
      x_bf, wqkv_bf, qkv_b, qkv_bf, M, 1536, 512, 12);

  attn_win<<<4096 * 4, 256, 0, stream>>>(qkv_bf, biasmask, attn_bf);

  // proj GEMM: (M,512,512); grid 1568*4 = 6272 (%8==0)
  gemm_bf16<false, false><<<1568 * 4, 256, 0, stream>>>(
      attn_bf, wproj_bf, proj_b, out, M, 512, 512, 4);

  // DIAGNOSTIC (R13): duplicate attn at 2x grid AFTER gemm2 consumed attn_bf.
  // Blocks i and i+16384 do identical work (bid mask) -> rewrites attn_bf
  // with identical data; deterministic, replay-safe (R9-proven pattern).
  // Duration ~2x attn (~470 us) -> ranks #1 in top-5, exposing attn_win's
  // occupancy / VALUBusy / MfmaUtil / FETCH / bank-conflict counters.
  attn_win<<<4096 * 8, 256, 0, stream>>>(qkv_bf, biasmask, attn_bf);
}

// Round 14
// 962.409 us; speedup vs baseline: 1.4463x; 1.4463x over previous
//
#include <hip/hip_runtime.h>
#include <hip/hip_bf16.h>
#include <stdint.h>

// ---------------- constants ----------------
#define DIMC 512
#define HEADS 16
#define HEAD_DIM 32
#define NTOK 49            // tokens per window (7x7)
#define SCALE 0.17677669529663687f   // 1/sqrt(32)
#define LOG2E 1.4426950408889634f
#define MTOK 200704        // 4096 * 49

typedef unsigned short u16;
typedef short bf16x8 __attribute__((ext_vector_type(8)));
typedef float f32x4 __attribute__((ext_vector_type(4)));
typedef u16 u16x4 __attribute__((ext_vector_type(4)));
typedef u16 u16x8 __attribute__((ext_vector_type(8)));

#define MFMA16(a, b, c) __builtin_amdgcn_mfma_f32_16x16x32_bf16((a), (b), (c), 0, 0, 0)

__device__ __forceinline__ u16 f2bf(float f) {
  __hip_bfloat16 h = __float2bfloat16(f);   // RNE
  u16 u;
  __builtin_memcpy(&u, &h, 2);
  return u;
}

__device__ __forceinline__ float bf2f(u16 u) {
  const uint32_t b = ((uint32_t)u) << 16;
  float f;
  __builtin_memcpy(&f, &b, 4);
  return f;
}

// async global->LDS, 16 bytes per lane (wave-uniform LDS base + lane*16)
__device__ __forceinline__ void gld16(const void* g, void* l) {
  __builtin_amdgcn_global_load_lds(
      (const __attribute__((address_space(1))) uint32_t*)g,
      (__attribute__((address_space(3))) uint32_t*)l, 16, 0, 0);
}

// ---------------- fp32 -> bf16 convert (grid-stride, 8 elems/thread/iter) ----
__global__ void cvt_f32_bf16(const float* __restrict__ in, u16* __restrict__ out, int n) {
  const int stride = gridDim.x * blockDim.x;
  for (int i = blockIdx.x * blockDim.x + threadIdx.x; i * 8 < n; i += stride) {
    const float4 v0 = ((const float4*)(in + i * 8))[0];
    const float4 v1 = ((const float4*)(in + i * 8))[1];
    u16x8 r;
    r[0] = f2bf(v0.x); r[1] = f2bf(v0.y); r[2] = f2bf(v0.z); r[3] = f2bf(v0.w);
    r[4] = f2bf(v1.x); r[5] = f2bf(v1.y); r[6] = f2bf(v1.z); r[7] = f2bf(v1.w);
    *(u16x8*)(out + i * 8) = r;
  }
}

// ---- bias+mask precompute, TRANSPOSED C-FRAGMENT order (for swapped QK^T) ----
// s[i][j] = mfma(K_j, Q_i) has C[row = k][col = q]; acc-init element
// (fi,fj,lane,r) = biasmask at q = fi*16 + (lane&15), k = fj*16 + (lane>>4)*4 + r.
// Pre-scaled by log2e (attn uses exp2); pad -> -1e30 (exp2 == exact 0).
__global__ void biasmask_kernel(const float* __restrict__ table, const float* __restrict__ mask,
                                u16* __restrict__ bm) {
  const int wm = blockIdx.x >> 4;   // 0..63
  const int h  = blockIdx.x & 15;   // 0..15
  for (int e = threadIdx.x; e < 4096; e += 256) {
    const int r = e & 3, lane = (e >> 2) & 63, fj = (e >> 8) & 3, fi = e >> 10;
    const int qrow = fi * 16 + (lane & 15);          // query index
    const int kcol = fj * 16 + (lane >> 4) * 4 + r;  // key index
    float v;
    if (qrow < NTOK && kcol < NTOK) {
      const int yi = qrow / 7, xi = qrow % 7, yj = kcol / 7, xj = kcol % 7;
      const int idx = (yi - yj + 6) * 13 + (xi - xj + 6);
      v = (table[idx * HEADS + h] + mask[wm * (NTOK * NTOK) + qrow * NTOK + kcol]) * LOG2E;
    } else {
      v = -1e30f;   // pad -> exp2 == exact 0
    }
    bm[(size_t)blockIdx.x * 4096 + e] = f2bf(v);
  }
}

// ---------------- GEMM: C[M,N] = A[M,K] @ B[N,K]^T + bias (all bf16 in) ------
// R2-PROVEN structure, FROZEN. HEADMAJOR epilogue (gemm1): scatter to
// [head][token][96] (q|k|v per head) for dense attn reads.
template<bool OUT_BF16, bool HEADMAJOR>
__global__ void gemm_bf16(const u16* __restrict__ Ap, const u16* __restrict__ Bp,
                          const float* __restrict__ bias, void* __restrict__ Cp,
                          int M, int N, int K, int nxt) {
  __shared__ u16 As[128 * 64];
  __shared__ u16 Bs[128 * 64];
  const int t = threadIdx.x;
  const int lane = t & 63;
  const int q = gridDim.x >> 3;
  const int lin = blockIdx.x;
  const int l = (lin & 7) * q + (lin >> 3);
  const int bm0 = (l / nxt) * 128;
  const int bn0 = (l % nxt) * 128;
  const int wv = t >> 6, wr = wv >> 1, wc = wv & 1;
  const int lr = lane & 15, lg = lane >> 4;

  f32x4 acc[4][4] = {};

  int soff[4];
#pragma unroll
  for (int k = 0; k < 4; ++k) {
    const int c = t + 256 * k;
    const int row = c >> 3, sub = c & 7;
    soff[k] = ((sub ^ (row & 7)) * 8);
  }

  const int nK = K >> 6;
  for (int kt = 0; kt < nK; ++kt) {
    const int k0 = kt << 6;
    __syncthreads();
#pragma unroll
    for (int k = 0; k < 4; ++k) {
      const int c = t + 256 * k;
      const int row = c >> 3;
      gld16(Ap + (size_t)(bm0 + row) * K + k0 + soff[k], As + c * 8);
      gld16(Bp + (size_t)(bn0 + row) * K + k0 + soff[k], Bs + c * 8);
    }
    __syncthreads();

#pragma unroll
    for (int kk = 0; kk < 2; ++kk) {
      bf16x8 af[4], bfr[4];
#pragma unroll
      for (int i = 0; i < 4; ++i) {
        const int row = wr * 64 + i * 16 + lr;
        af[i] = *(const bf16x8*)&As[row * 64 + (((kk * 4 + lg) ^ (row & 7)) << 3)];
      }
#pragma unroll
      for (int j = 0; j < 4; ++j) {
        const int row = wc * 64 + j * 16 + lr;
        bfr[j] = *(const bf16x8*)&Bs[row * 64 + (((kk * 4 + lg) ^ (row & 7)) << 3)];
      }
#pragma unroll
      for (int i = 0; i < 4; ++i)
#pragma unroll
        for (int j = 0; j < 4; ++j)
          acc[i][j] = MFMA16(af[i], bfr[j], acc[i][j]);
    }
  }

  // epilogue: D row = (lane>>4)*4 + r, col = lane&15 (m89-verified layout)
#pragma unroll
  for (int j = 0; j < 4; ++j) {
    const int col = bn0 + wc * 64 + j * 16 + lr;
    const float bv = bias[col];
    const int p = col >> 9, hh = (col & 511) >> 5, d = col & 31;
    const float sc = (HEADMAJOR && p == 0) ? SCALE * LOG2E : 1.0f;
#pragma unroll
    for (int i = 0; i < 4; ++i) {
      const int row0 = bm0 + wr * 64 + i * 16 + lg * 4;
#pragma unroll
      for (int r = 0; r < 4; ++r) {
        const float val = (acc[i][j][r] + bv) * sc;
        if (HEADMAJOR) {
          ((u16*)Cp)[((size_t)hh * MTOK + row0 + r) * 96 + p * 32 + d] = f2bf(val);
        } else if (OUT_BF16) {
          ((u16*)Cp)[(size_t)(row0 + r) * N + col] = f2bf(val);
        } else {
          ((float*)Cp)[(size_t)(row0 + r) * N + col] = val;
        }
      }
    }
  }
}

// ---------------- fused window attention (v6: swapped QK^T) ----------
// 1 wave per (window, head). qkv: [head][token][96] bf16 (q pre-scaled by
// SCALE*log2e). R13 PMC diagnosis: traffic ideal, BW 46%, VALUBusy 39% --
// the serializer was the P-store (64 scalar swizzled ds_write_b16 + addr
// math). v6: S computed SWAPPED (mfma(K,Q) -> C[k][q]) so each lane holds
// k-CONSECUTIVE P runs for its own q -> P-store becomes 16 vectorized
// ds_write_b64 at linear [q][72] addresses (stride 72 -> 2-way conflicts,
// free). PV / ones-column row-sum / output unchanged.
__launch_bounds__(256, 4)
__global__ void attn_win(const u16* __restrict__ qkv, const u16* __restrict__ bmfrag,
                         u16* __restrict__ aout) {
  __shared__ u16 P[4][64 * 72];    // per-wave P tile: [q][k], stride 72
  const int t = threadIdx.x, lane = t & 63, wv = t >> 6;
  const int lr = lane & 15, lg = lane >> 4;
  const int w = blockIdx.x >> 2;
  const int h = ((blockIdx.x & 3) << 2) + wv;
  const size_t baseh = ((size_t)h * MTOK + (size_t)w * NTOK) * 96;

  // acc init = TRANSPOSED bias+mask fragments (bf16, fragment-ordered)
  const u16* bmp = bmfrag + (((size_t)(w & 63) * 16 + h) << 12);
  f32x4 s[4][4];
#pragma unroll
  for (int i = 0; i < 4; ++i)
#pragma unroll
    for (int j = 0; j < 4; ++j) {
      const u16x4 b4 = *(const u16x4*)&bmp[((i * 4 + j) * 64 + lane) * 4];
#pragma unroll
      for (int r = 0; r < 4; ++r) s[i][j][r] = bf2f(b4[r]);
    }

  const bf16x8 zf = {};
  bf16x8 qf[4], kf[4];
#pragma unroll
  for (int i = 0; i < 4; ++i) {
    const int row = i * 16 + lr;
    const size_t roff = baseh + (size_t)row * 96 + lg * 8;
    qf[i] = (row < NTOK) ? *(const bf16x8*)&qkv[roff] : zf;        // Q(row, d..)
    kf[i] = (row < NTOK) ? *(const bf16x8*)&qkv[roff + 32] : zf;   // K(row, d..)
  }

  // SWAPPED QK^T: s[i][j] = K_j . Q_i^T + bias^T  ->  C[k = j*16+lg*4+r][q = i*16+lr]
  __builtin_amdgcn_s_setprio(1);
#pragma unroll
  for (int i = 0; i < 4; ++i)
#pragma unroll
    for (int j = 0; j < 4; ++j)
      s[i][j] = MFMA16(kf[j], qf[i], s[i][j]);
  __builtin_amdgcn_s_setprio(0);

  // P = exp2(S) -> LDS [q][k] stride 72; per (i,j) one VECTOR ds_write_b64
  // (lane's 4 values are k-consecutive at fixed q -- the v6 win)
  u16* Pw = &P[wv][0];
#pragma unroll
  for (int i = 0; i < 4; ++i)
#pragma unroll
    for (int j = 0; j < 4; ++j) {
      u16x4 pk;
#pragma unroll
      for (int r = 0; r < 4; ++r)
        pk[r] = f2bf(__builtin_amdgcn_exp2f(s[i][j][r]));
      *(u16x4*)&Pw[(i * 16 + lr) * 72 + j * 16 + lg * 4] = pk;
    }

  // V as B-fragments, direct from global (after s[] dies; TLP hides latency).
  bf16x8 vf[2][2];
#pragma unroll
  for (int ks = 0; ks < 2; ++ks)
#pragma unroll
    for (int dn = 0; dn < 2; ++dn)
#pragma unroll
      for (int e = 0; e < 8; ++e) {
        int kk = ks * 32 + lg * 8 + e;
        kk = kk < NTOK ? kk : 0;
        vf[ks][dn][e] = (short)qkv[baseh + (size_t)kk * 96 + 64 + dn * 16 + lr];
      }

  // PV + row-sum: out[q][d] = sum_k P[q][k] V[k][d]; osum[q] = sum_k P[q][k]
  bf16x8 ones;
#pragma unroll
  for (int e = 0; e < 8; ++e) ones[e] = (short)0x3F80;  // bf16 1.0
  f32x4 o[4][2] = {};
  f32x4 osum[4] = {};
#pragma unroll
  for (int ks = 0; ks < 2; ++ks) {
    __builtin_amdgcn_s_setprio(1);
#pragma unroll
    for (int i = 0; i < 4; ++i) {
      // A-frag: row q = i*16+lr, k = ks*32 + lg*8 + e -- one ds_read_b128
      const bf16x8 pa = *(const bf16x8*)&Pw[(i * 16 + lr) * 72 + ks * 32 + lg * 8];
#pragma unroll
      for (int dn = 0; dn < 2; ++dn)
        o[i][dn] = MFMA16(pa, vf[ks][dn], o[i][dn]);
      osum[i] = MFMA16(pa, ones, osum[i]);     // row-sum in C-layout
    }
    __builtin_amdgcn_s_setprio(0);
  }

  // store attention output (normalize here) -> [token][h*32+d] bf16
#pragma unroll
  for (int i = 0; i < 4; ++i)
#pragma unroll
    for (int r = 0; r < 4; ++r) {
      const int row = i * 16 + lg * 4 + r;
      if (row < NTOK) {
        const float rinv = __builtin_amdgcn_rcpf(osum[i][r]);
        const size_t ob = ((size_t)w * NTOK + row) * DIMC + h * HEAD_DIM;
#pragma unroll
        for (int dn = 0; dn < 2; ++dn)
          aout[ob + dn * 16 + lr] = f2bf(o[i][dn][r] * rinv);
      }
    }
}

// ---------------- launch ----------------
extern "C" void kernel_launch(void* const* d_in, const int* in_sizes, int n_in,
                              void* d_out, int out_size, void* d_ws, size_t ws_size,
                              hipStream_t stream) {
  const float* x      = (const float*)d_in[0];   // (4096,49,512)
  const float* mask   = (const float*)d_in[1];   // (64,49,49)
  const float* qkv_w  = (const float*)d_in[2];   // (1536,512)
  const float* qkv_b  = (const float*)d_in[3];   // (1536,)
  const float* table  = (const float*)d_in[4];   // (169,16)
  const float* proj_w = (const float*)d_in[5];   // (512,512)
  const float* proj_b = (const float*)d_in[6];   // (512,)
  float* out = (float*)d_out;

  const int M = MTOK;   // 200704

  char* ws = (char*)d_ws;
  u16*   qkv_bf   = (u16*)ws;                         // 16*200704*96*2 = 616,562,688
  u16*   wqkv_bf  = (u16*)(ws + 616562688ull);        // 1536*512*2    = 1,572,864
  u16*   wproj_bf = (u16*)(ws + 618135552ull);        // 512*512*2     = 524,288
  u16*   biasmask = (u16*)(ws + 618659840ull);        // 1024*4096*2   = 8,388,608
  // x_bf and attn_bf SHARE this region (disjoint lifetimes, same size):
  u16*   x_bf     = (u16*)(ws + 627048448ull);        // 200704*512*2  = 205,520,896
  u16*   attn_bf  = x_bf;
  // total 832,569,344 bytes

  cvt_f32_bf16<<<768, 256, 0, stream>>>(qkv_w, wqkv_bf, 1536 * 512);
  cvt_f32_bf16<<<256, 256, 0, stream>>>(proj_w, wproj_bf, 512 * 512);
  biasmask_kernel<<<1024, 256, 0, stream>>>(table, mask, biasmask);
  cvt_f32_bf16<<<1792, 256, 0, stream>>>(x, x_bf, M * DIMC);

  // QKV GEMM -> head-major layout: (M,1536,512); grid 1568*12 = 18816 (%8==0)
  gemm_bf16<true, true><<<1568 * 12, 256, 0, stream>>>(
      x_bf, wqkv_bf, qkv_b, qkv_bf, M, 1536, 512, 12);

  attn_win<<<4096 * 4, 256, 0, stream>>>(qkv_bf, biasmask, attn_bf);

  // proj GEMM: (M,512,512); grid 1568*4 = 6272 (%8==0)
  gemm_bf16<false, false><<<1568 * 4, 256, 0, stream>>>(
      attn_bf, wproj_bf, proj_b, out, M, 512, 512, 4);
}